// Round 7
// baseline (250.219 us; speedup 1.0000x reference)
//
#include <hip/hip_runtime.h>

#define BATCH 32
#define NPTS 131072           // 2^17 points per cloud
#define RES 24
#define R3 (RES*RES*RES)      // 13824
#define NPART 4               // qx slabs of 6
#define SLAB 6
#define PCELLS (SLAB*RES*RES) // 3456 cells -> 55296 B LDS
#define NCHUNK 4
#define CPTS (NPTS/NCHUNK)    // 32768 points per chunk
#define NBLK_PER_B 16
#define CHUNK (NPTS/NBLK_PER_B)  // 8192 (mean/max kernels)
#define NSCAT (BATCH*NCHUNK*NPART)   // 512 scatter blocks

// ws layout (bytes):
//   [0,     12288)  double partial[512][3]
//   [12288, 13056)  double mean[32][3]
//   [13056, 13312)  ull    maxsq[32]
//   [16384, ...  )  float  accum — private: [512][3456][4] (28.3 MB)
//                          fallback (small ws): shared [32*13824][4] (7.1 MB)
#define WS_PARTIAL 0
#define WS_MEAN    12288
#define WS_MAXSQ   13056
#define WS_ACCUM   16384
#define PRIV_BYTES ((size_t)NSCAT * PCELLS * 4 * sizeof(float))
#define SHARED_BYTES ((size_t)BATCH * R3 * 4 * sizeof(float))

__global__ __launch_bounds__(256) void k_mean(const float* __restrict__ pts,
                                              double* __restrict__ partial) {
    int blk = blockIdx.x;
    int b = blk >> 4, c = blk & 15;
    const float4* base = (const float4*)(pts + ((size_t)b * NPTS + (size_t)c * CHUNK) * 6);
    double s0 = 0, s1 = 0, s2 = 0;
    for (int i = threadIdx.x; i < CHUNK / 2; i += 256) {
        float4 v0 = base[(size_t)i * 3];
        float4 v1 = base[(size_t)i * 3 + 1];
        float4 v2 = base[(size_t)i * 3 + 2];
        s0 += (double)v0.x + (double)v1.z;
        s1 += (double)v0.y + (double)v1.w;
        s2 += (double)v0.z + (double)v2.x;
    }
    for (int off = 32; off; off >>= 1) {
        s0 += __shfl_down(s0, off);
        s1 += __shfl_down(s1, off);
        s2 += __shfl_down(s2, off);
    }
    __shared__ double sh[4][3];
    int lane = threadIdx.x & 63, w = threadIdx.x >> 6;
    if (lane == 0) { sh[w][0] = s0; sh[w][1] = s1; sh[w][2] = s2; }
    __syncthreads();
    if (threadIdx.x == 0) {
        double t0 = 0, t1 = 0, t2 = 0;
        for (int q = 0; q < 4; q++) { t0 += sh[q][0]; t1 += sh[q][1]; t2 += sh[q][2]; }
        partial[(size_t)blk * 3 + 0] = t0;
        partial[(size_t)blk * 3 + 1] = t1;
        partial[(size_t)blk * 3 + 2] = t2;
    }
}

__global__ __launch_bounds__(64) void k_meanred(const double* __restrict__ partial,
                                                double* __restrict__ mean) {
    int b = threadIdx.x;
    if (b >= BATCH) return;
    double t0 = 0, t1 = 0, t2 = 0;
    for (int c = 0; c < NBLK_PER_B; c++) {
        const double* p = partial + ((size_t)b * NBLK_PER_B + c) * 3;
        t0 += p[0]; t1 += p[1]; t2 += p[2];
    }
    mean[b * 3 + 0] = t0 / (double)NPTS;
    mean[b * 3 + 1] = t1 / (double)NPTS;
    mean[b * 3 + 2] = t2 / (double)NPTS;
}

__global__ __launch_bounds__(256) void k_max(const float* __restrict__ pts,
                                             const double* __restrict__ mean,
                                             unsigned long long* __restrict__ maxsq) {
    int blk = blockIdx.x;
    int b = blk >> 4, c = blk & 15;
    double mx = mean[b * 3], my = mean[b * 3 + 1], mz = mean[b * 3 + 2];
    const float4* base = (const float4*)(pts + ((size_t)b * NPTS + (size_t)c * CHUNK) * 6);
    double m = 0.0;
    for (int i = threadIdx.x; i < CHUNK / 2; i += 256) {
        float4 v0 = base[(size_t)i * 3];
        float4 v1 = base[(size_t)i * 3 + 1];
        float4 v2 = base[(size_t)i * 3 + 2];
        double dx = (double)v0.x - mx, dy = (double)v0.y - my, dz = (double)v0.z - mz;
        m = fmax(m, dx * dx + dy * dy + dz * dz);
        dx = (double)v1.z - mx; dy = (double)v1.w - my; dz = (double)v2.x - mz;
        m = fmax(m, dx * dx + dy * dy + dz * dz);
    }
    for (int off = 32; off; off >>= 1)
        m = fmax(m, __shfl_down(m, off));
    __shared__ double sh[4];
    int lane = threadIdx.x & 63, w = threadIdx.x >> 6;
    if (lane == 0) sh[w] = m;
    __syncthreads();
    if (threadIdx.x == 0) {
        double t = fmax(fmax(sh[0], sh[1]), fmax(sh[2], sh[3]));
        atomicMax(&maxsq[b], (unsigned long long)__double_as_longlong(t));
    }
}

// Shared body: stream chunk, LDS-accumulate slab cells. ATOMIC=false stores the
// whole LDS grid to a private region (no atomics); ATOMIC=true is the fallback
// merge into a shared per-batch accum.
template <bool ATOMIC>
__global__ __launch_bounds__(1024, 8) void k_scatter_lds(const float* __restrict__ pts,
                                                         const double* __restrict__ mean,
                                                         const unsigned long long* __restrict__ maxsq,
                                                         float* __restrict__ accum) {
    __shared__ float acc[PCELLS][4];
    int blk = blockIdx.x;
    int b = blk >> 4;
    int ch = (blk >> 2) & 3;
    int p = blk & 3;                 // qx in [6p, 6p+6)
    for (int c = threadIdx.x; c < PCELLS * 4; c += 1024)
        ((float*)acc)[c] = 0.0f;
    __syncthreads();

    double mx = mean[b * 3], my = mean[b * 3 + 1], mz = mean[b * 3 + 2];
    double denom = 2.0 * sqrt(__longlong_as_double((long long)maxsq[b]));
    double xlo = mx + denom * (((double)(6 * p) - 0.5) / 24.0 - 0.5);
    double xhi = mx + denom * (((double)(6 * p) + 5.5) / 24.0 - 0.5);
    float flo = (p == 0)         ? -3.0e38f : (float)(xlo - 1e-4);
    float fhi = (p == NPART - 1) ?  3.0e38f : (float)(xhi + 1e-4);

    const float4* base = (const float4*)(pts + ((size_t)b * NPTS + (size_t)ch * CPTS) * 6);

    auto point = [&](float x, float y, float z, float f1, float f2, float f3) {
        if (x >= flo && x <= fhi) {
            double vx = ((double)x - mx) / denom + 0.5;
            vx = fmin(fmax(vx * 24.0, 0.0), 23.0);
            int qx = (int)rint(vx);
            if (qx >= 6 * p && qx < 6 * p + 6) {
                double vy = ((double)y - my) / denom + 0.5;
                double vz = ((double)z - mz) / denom + 0.5;
                vy = fmin(fmax(vy * 24.0, 0.0), 23.0);
                vz = fmin(fmax(vz * 24.0, 0.0), 23.0);
                int qy = (int)rint(vy);
                int qz = (int)rint(vz);
                int l = (qx - 6 * p) * (RES * RES) + qy * RES + qz;
                atomicAdd(&acc[l][0], 1.0f);
                atomicAdd(&acc[l][1], f1);
                atomicAdd(&acc[l][2], f2);
                atomicAdd(&acc[l][3], f3);
            }
        }
    };

    for (int it = 0; it < 8; ++it) {
        int pairA = it * 2048 + threadIdx.x;
        int pairB = pairA + 1024;
        float4 a0 = base[(size_t)pairA * 3];
        float4 a1 = base[(size_t)pairA * 3 + 1];
        float4 a2 = base[(size_t)pairA * 3 + 2];
        float4 b0 = base[(size_t)pairB * 3];
        float4 b1 = base[(size_t)pairB * 3 + 1];
        float4 b2 = base[(size_t)pairB * 3 + 2];
        point(a0.x, a0.y, a0.z, a0.w, a1.x, a1.y);
        point(a1.z, a1.w, a2.x, a2.y, a2.z, a2.w);
        point(b0.x, b0.y, b0.z, b0.w, b1.x, b1.y);
        point(b1.z, b1.w, b2.x, b2.y, b2.z, b2.w);
    }
    __syncthreads();

    if (ATOMIC) {
        float* gacc = accum + ((size_t)b * R3 + (size_t)p * PCELLS) * 4;
        for (int c = threadIdx.x; c < PCELLS * 4; c += 1024) {
            float v = ((float*)acc)[c];
            if (v != 0.0f) atomicAdd(&gacc[c], v);
        }
    } else {
        // private region: plain coalesced float4 stores, no atomics
        float4* gacc = (float4*)(accum + (size_t)blk * PCELLS * 4);
        const float4* lacc = (const float4*)acc;
        for (int c = threadIdx.x; c < PCELLS; c += 1024)
            gacc[c] = lacc[c];
    }
}

// Private-region finalize: sum the NCHUNK chunk copies per cell, normalize, write.
__global__ __launch_bounds__(256) void k_final_priv(const float* __restrict__ accum,
                                                    float* __restrict__ out) {
    int cell = blockIdx.x * 256 + threadIdx.x;  // < BATCH*R3
    int b = cell / R3;
    int r = cell - b * R3;
    int p = r / PCELLS;
    int l = r - p * PCELLS;
    const float4* a = (const float4*)accum;
    float4 s = make_float4(0.f, 0.f, 0.f, 0.f);
    #pragma unroll
    for (int ch = 0; ch < NCHUNK; ch++) {
        float4 v = a[((size_t)((b * NCHUNK + ch) * NPART + p)) * PCELLS + l];
        s.x += v.x; s.y += v.y; s.z += v.z; s.w += v.w;
    }
    size_t obase = (size_t)b * 4 * R3 + r;
    if (s.x > 0.0f) {
        out[obase]          = 1.0f;
        out[obase + R3]     = s.y / s.x;
        out[obase + 2 * R3] = s.z / s.x;
        out[obase + 3 * R3] = s.w / s.x;
    } else {
        out[obase]          = 0.0f;
        out[obase + R3]     = 0.0f;
        out[obase + 2 * R3] = 0.0f;
        out[obase + 3 * R3] = 0.0f;
    }
}

// Fallback finalize (shared accum)
__global__ __launch_bounds__(256) void k_final_sum(const float* __restrict__ accum,
                                                   float* __restrict__ out) {
    int cell = blockIdx.x * 256 + threadIdx.x;
    const float4 a = ((const float4*)accum)[cell];
    float cnt = a.x;
    int b = cell / R3;
    int r = cell - b * R3;
    size_t obase = (size_t)b * 4 * R3 + r;
    if (cnt > 0.0f) {
        out[obase]          = 1.0f;
        out[obase + R3]     = a.y / cnt;
        out[obase + 2 * R3] = a.z / cnt;
        out[obase + 3 * R3] = a.w / cnt;
    } else {
        out[obase]          = 0.0f;
        out[obase + R3]     = 0.0f;
        out[obase + 2 * R3] = 0.0f;
        out[obase + 3 * R3] = 0.0f;
    }
}

extern "C" void kernel_launch(void* const* d_in, const int* in_sizes, int n_in,
                              void* d_out, int out_size, void* d_ws, size_t ws_size,
                              hipStream_t stream) {
    const float* pts = (const float*)d_in[0];
    float* out = (float*)d_out;
    char* ws = (char*)d_ws;
    double* partial = (double*)(ws + WS_PARTIAL);
    double* mean = (double*)(ws + WS_MEAN);
    unsigned long long* maxsq = (unsigned long long*)(ws + WS_MAXSQ);
    float* accum = (float*)(ws + WS_ACCUM);
    bool priv = ws_size >= (size_t)WS_ACCUM + PRIV_BYTES;

    if (priv) {
        // private regions fully overwritten -> only maxsq needs zeroing
        hipMemsetAsync(ws + WS_MAXSQ, 0, BATCH * sizeof(unsigned long long), stream);
    } else {
        hipMemsetAsync(ws + WS_MAXSQ, 0, (WS_ACCUM - WS_MAXSQ) + SHARED_BYTES, stream);
    }

    k_mean<<<BATCH * NBLK_PER_B, 256, 0, stream>>>(pts, partial);
    k_meanred<<<1, 64, 0, stream>>>(partial, mean);
    k_max<<<BATCH * NBLK_PER_B, 256, 0, stream>>>(pts, mean, maxsq);
    if (priv) {
        k_scatter_lds<false><<<NSCAT, 1024, 0, stream>>>(pts, mean, maxsq, accum);
        k_final_priv<<<(BATCH * R3) / 256, 256, 0, stream>>>(accum, out);
    } else {
        k_scatter_lds<true><<<NSCAT, 1024, 0, stream>>>(pts, mean, maxsq, accum);
        k_final_sum<<<(BATCH * R3) / 256, 256, 0, stream>>>(accum, out);
    }
}

// Round 8
// 149.470 us; speedup vs baseline: 1.6740x; 1.6740x over previous
//
#include <hip/hip_runtime.h>

#define BATCH 32
#define NPTS 131072           // 2^17 points per cloud
#define RES 24
#define R3 (RES*RES*RES)      // 13824
#define NPART 4               // interleaved partition: p = cell & 3 (balanced)
#define PCELLS (R3/NPART)     // 3456 cells -> 55296 B LDS
#define NCHUNK 4
#define CPTS (NPTS/NCHUNK)    // 32768 points per chunk
#define NBLK_PER_B 64
#define MCHUNK (NPTS/NBLK_PER_B) // 2048 (mean/max kernels)
#define NSCAT (BATCH*NCHUNK*NPART)   // 512 scatter blocks

// ws layout (bytes):
//   [0,     49152)  double partial[2048][3]
//   [49152, 49920)  double mean[32][3]
//   [49920, 50176)  ull    maxsq[32]
//   [65536, ...  )  float  accum — private: [512][3456][4] (28.3 MB)
//                          fallback (small ws): shared [32*13824][4] (7.1 MB)
#define WS_PARTIAL 0
#define WS_MEAN    49152
#define WS_MAXSQ   49920
#define WS_ACCUM   65536
#define PRIV_BYTES ((size_t)NSCAT * PCELLS * 4 * sizeof(float))
#define SHARED_BYTES ((size_t)BATCH * R3 * 4 * sizeof(float))

__global__ __launch_bounds__(256) void k_mean(const float* __restrict__ pts,
                                              double* __restrict__ partial) {
    int blk = blockIdx.x;
    int b = blk >> 6, c = blk & 63;
    const float4* base = (const float4*)(pts + ((size_t)b * NPTS + (size_t)c * MCHUNK) * 6);
    double s0 = 0, s1 = 0, s2 = 0;
    for (int i = threadIdx.x; i < MCHUNK / 2; i += 256) {
        float4 v0 = base[(size_t)i * 3];
        float4 v1 = base[(size_t)i * 3 + 1];
        float4 v2 = base[(size_t)i * 3 + 2];
        s0 += (double)v0.x + (double)v1.z;
        s1 += (double)v0.y + (double)v1.w;
        s2 += (double)v0.z + (double)v2.x;
    }
    for (int off = 32; off; off >>= 1) {
        s0 += __shfl_down(s0, off);
        s1 += __shfl_down(s1, off);
        s2 += __shfl_down(s2, off);
    }
    __shared__ double sh[4][3];
    int lane = threadIdx.x & 63, w = threadIdx.x >> 6;
    if (lane == 0) { sh[w][0] = s0; sh[w][1] = s1; sh[w][2] = s2; }
    __syncthreads();
    if (threadIdx.x == 0) {
        double t0 = 0, t1 = 0, t2 = 0;
        for (int q = 0; q < 4; q++) { t0 += sh[q][0]; t1 += sh[q][1]; t2 += sh[q][2]; }
        partial[(size_t)blk * 3 + 0] = t0;
        partial[(size_t)blk * 3 + 1] = t1;
        partial[(size_t)blk * 3 + 2] = t2;
    }
}

__global__ __launch_bounds__(64) void k_meanred(const double* __restrict__ partial,
                                                double* __restrict__ mean) {
    int b = threadIdx.x;
    if (b >= BATCH) return;
    double t0 = 0, t1 = 0, t2 = 0;
    for (int c = 0; c < NBLK_PER_B; c++) {
        const double* p = partial + ((size_t)b * NBLK_PER_B + c) * 3;
        t0 += p[0]; t1 += p[1]; t2 += p[2];
    }
    mean[b * 3 + 0] = t0 / (double)NPTS;
    mean[b * 3 + 1] = t1 / (double)NPTS;
    mean[b * 3 + 2] = t2 / (double)NPTS;
}

__global__ __launch_bounds__(256) void k_max(const float* __restrict__ pts,
                                             const double* __restrict__ mean,
                                             unsigned long long* __restrict__ maxsq) {
    int blk = blockIdx.x;
    int b = blk >> 6, c = blk & 63;
    double mx = mean[b * 3], my = mean[b * 3 + 1], mz = mean[b * 3 + 2];
    const float4* base = (const float4*)(pts + ((size_t)b * NPTS + (size_t)c * MCHUNK) * 6);
    double m = 0.0;
    for (int i = threadIdx.x; i < MCHUNK / 2; i += 256) {
        float4 v0 = base[(size_t)i * 3];
        float4 v1 = base[(size_t)i * 3 + 1];
        float4 v2 = base[(size_t)i * 3 + 2];
        double dx = (double)v0.x - mx, dy = (double)v0.y - my, dz = (double)v0.z - mz;
        m = fmax(m, dx * dx + dy * dy + dz * dz);
        dx = (double)v1.z - mx; dy = (double)v1.w - my; dz = (double)v2.x - mz;
        m = fmax(m, dx * dx + dy * dy + dz * dz);
    }
    for (int off = 32; off; off >>= 1)
        m = fmax(m, __shfl_down(m, off));
    __shared__ double sh[4];
    int lane = threadIdx.x & 63, w = threadIdx.x >> 6;
    if (lane == 0) sh[w] = m;
    __syncthreads();
    if (threadIdx.x == 0) {
        double t = fmax(fmax(sh[0], sh[1]), fmax(sh[2], sh[3]));
        atomicMax(&maxsq[b], (unsigned long long)__double_as_longlong(t));
    }
}

// One block per (batch, chunk, part). p = cell & 3 interleaved partition
// (load-balanced for any distribution). Unconditional 3-axis f64 transform
// (fma with precomputed 1/denom — no divides), single membership test,
// LDS accumulate, then private-region store (no atomics).
template <bool ATOMIC>
__global__ __launch_bounds__(1024, 8) void k_scatter_lds(const float* __restrict__ pts,
                                                         const double* __restrict__ mean,
                                                         const unsigned long long* __restrict__ maxsq,
                                                         float* __restrict__ accum) {
    __shared__ float acc[PCELLS][4];
    int blk = blockIdx.x;
    int b = blk >> 4;
    int ch = (blk >> 2) & 3;
    int p = blk & 3;
    for (int c = threadIdx.x; c < PCELLS * 4; c += 1024)
        ((float*)acc)[c] = 0.0f;
    __syncthreads();

    double mx = mean[b * 3], my = mean[b * 3 + 1], mz = mean[b * 3 + 2];
    double inv = 1.0 / (2.0 * sqrt(__longlong_as_double((long long)maxsq[b])));

    const float4* base = (const float4*)(pts + ((size_t)b * NPTS + (size_t)ch * CPTS) * 6);

    auto point = [&](float x, float y, float z, float f1, float f2, float f3) {
        double vx = fma((double)x - mx, inv, 0.5) * 24.0;
        double vy = fma((double)y - my, inv, 0.5) * 24.0;
        double vz = fma((double)z - mz, inv, 0.5) * 24.0;
        vx = fmin(fmax(vx, 0.0), 23.0);
        vy = fmin(fmax(vy, 0.0), 23.0);
        vz = fmin(fmax(vz, 0.0), 23.0);
        int qx = (int)rint(vx);
        int qy = (int)rint(vy);
        int qz = (int)rint(vz);
        int cell = qx * (RES * RES) + qy * RES + qz;
        if ((cell & 3) == p) {
            int l = cell >> 2;
            atomicAdd(&acc[l][0], 1.0f);
            atomicAdd(&acc[l][1], f1);
            atomicAdd(&acc[l][2], f2);
            atomicAdd(&acc[l][3], f3);
        }
    };

    for (int it = 0; it < 8; ++it) {
        int pairA = it * 2048 + threadIdx.x;
        int pairB = pairA + 1024;
        float4 a0 = base[(size_t)pairA * 3];
        float4 a1 = base[(size_t)pairA * 3 + 1];
        float4 a2 = base[(size_t)pairA * 3 + 2];
        float4 b0 = base[(size_t)pairB * 3];
        float4 b1 = base[(size_t)pairB * 3 + 1];
        float4 b2 = base[(size_t)pairB * 3 + 2];
        point(a0.x, a0.y, a0.z, a0.w, a1.x, a1.y);
        point(a1.z, a1.w, a2.x, a2.y, a2.z, a2.w);
        point(b0.x, b0.y, b0.z, b0.w, b1.x, b1.y);
        point(b1.z, b1.w, b2.x, b2.y, b2.z, b2.w);
    }
    __syncthreads();

    if (ATOMIC) {
        // fallback: merge into shared per-batch accum; cell = (l<<2)|p
        for (int c = threadIdx.x; c < PCELLS * 4; c += 1024) {
            int l = c >> 2, f = c & 3;
            float v = acc[l][f];
            if (v != 0.0f)
                atomicAdd(&accum[((size_t)b * R3 + ((l << 2) | p)) * 4 + f], v);
        }
    } else {
        float4* gacc = (float4*)(accum + (size_t)blk * PCELLS * 4);
        const float4* lacc = (const float4*)acc;
        for (int c = threadIdx.x; c < PCELLS; c += 1024)
            gacc[c] = lacc[c];
    }
}

// Private-region finalize: cell r -> partition p = r&3, local l = r>>2.
__global__ __launch_bounds__(256) void k_final_priv(const float* __restrict__ accum,
                                                    float* __restrict__ out) {
    int cell = blockIdx.x * 256 + threadIdx.x;  // < BATCH*R3
    int b = cell / R3;
    int r = cell - b * R3;
    int p = r & 3;
    int l = r >> 2;
    const float4* a = (const float4*)accum;
    float4 s = make_float4(0.f, 0.f, 0.f, 0.f);
    #pragma unroll
    for (int ch = 0; ch < NCHUNK; ch++) {
        float4 v = a[((size_t)((b * NCHUNK + ch) * NPART + p)) * PCELLS + l];
        s.x += v.x; s.y += v.y; s.z += v.z; s.w += v.w;
    }
    size_t obase = (size_t)b * 4 * R3 + r;
    if (s.x > 0.0f) {
        out[obase]          = 1.0f;
        out[obase + R3]     = s.y / s.x;
        out[obase + 2 * R3] = s.z / s.x;
        out[obase + 3 * R3] = s.w / s.x;
    } else {
        out[obase]          = 0.0f;
        out[obase + R3]     = 0.0f;
        out[obase + 2 * R3] = 0.0f;
        out[obase + 3 * R3] = 0.0f;
    }
}

// Fallback finalize (shared accum)
__global__ __launch_bounds__(256) void k_final_sum(const float* __restrict__ accum,
                                                   float* __restrict__ out) {
    int cell = blockIdx.x * 256 + threadIdx.x;
    const float4 a = ((const float4*)accum)[cell];
    float cnt = a.x;
    int b = cell / R3;
    int r = cell - b * R3;
    size_t obase = (size_t)b * 4 * R3 + r;
    if (cnt > 0.0f) {
        out[obase]          = 1.0f;
        out[obase + R3]     = a.y / cnt;
        out[obase + 2 * R3] = a.z / cnt;
        out[obase + 3 * R3] = a.w / cnt;
    } else {
        out[obase]          = 0.0f;
        out[obase + R3]     = 0.0f;
        out[obase + 2 * R3] = 0.0f;
        out[obase + 3 * R3] = 0.0f;
    }
}

extern "C" void kernel_launch(void* const* d_in, const int* in_sizes, int n_in,
                              void* d_out, int out_size, void* d_ws, size_t ws_size,
                              hipStream_t stream) {
    const float* pts = (const float*)d_in[0];
    float* out = (float*)d_out;
    char* ws = (char*)d_ws;
    double* partial = (double*)(ws + WS_PARTIAL);
    double* mean = (double*)(ws + WS_MEAN);
    unsigned long long* maxsq = (unsigned long long*)(ws + WS_MAXSQ);
    float* accum = (float*)(ws + WS_ACCUM);
    bool priv = ws_size >= (size_t)WS_ACCUM + PRIV_BYTES;

    if (priv) {
        hipMemsetAsync(ws + WS_MAXSQ, 0, BATCH * sizeof(unsigned long long), stream);
    } else {
        hipMemsetAsync(ws + WS_MAXSQ, 0, (WS_ACCUM - WS_MAXSQ) + SHARED_BYTES, stream);
    }

    k_mean<<<BATCH * NBLK_PER_B, 256, 0, stream>>>(pts, partial);
    k_meanred<<<1, 64, 0, stream>>>(partial, mean);
    k_max<<<BATCH * NBLK_PER_B, 256, 0, stream>>>(pts, mean, maxsq);
    if (priv) {
        k_scatter_lds<false><<<NSCAT, 1024, 0, stream>>>(pts, mean, maxsq, accum);
        k_final_priv<<<(BATCH * R3) / 256, 256, 0, stream>>>(accum, out);
    } else {
        k_scatter_lds<true><<<NSCAT, 1024, 0, stream>>>(pts, mean, maxsq, accum);
        k_final_sum<<<(BATCH * R3) / 256, 256, 0, stream>>>(accum, out);
    }
}

// Round 9
// 148.959 us; speedup vs baseline: 1.6798x; 1.0034x over previous
//
#include <hip/hip_runtime.h>

#define BATCH 32
#define NPTS 131072           // 2^17 points per cloud
#define RES 24
#define R3 (RES*RES*RES)      // 13824
#define NPART 2               // interleaved partition: p = cell & 1 (balanced)
#define PCELLS (R3/NPART)     // 6912 cells -> 110592 B LDS (gfx950: 160 KiB/CU)
#define NCHUNK 4
#define CPTS (NPTS/NCHUNK)    // 32768 points per chunk
#define NBLK_PER_B 64
#define MCHUNK (NPTS/NBLK_PER_B) // 2048 (mean/max kernels)
#define NSCAT (BATCH*NCHUNK*NPART)   // 256 scatter blocks = 1 per CU

// ws layout (bytes):
//   [0,     49152)  double partial[2048][3]
//   [49152, 49920)  double mean[32][3]
//   [49920, 50176)  ull    maxsq[32]
//   [65536, ...  )  float  accum — private: [256][6912][4] (28.3 MB, same as r8)
//                          fallback (small ws): shared [32*13824][4] (7.1 MB)
#define WS_PARTIAL 0
#define WS_MEAN    49152
#define WS_MAXSQ   49920
#define WS_ACCUM   65536
#define PRIV_BYTES ((size_t)NSCAT * PCELLS * 4 * sizeof(float))
#define SHARED_BYTES ((size_t)BATCH * R3 * 4 * sizeof(float))

__global__ __launch_bounds__(256) void k_mean(const float* __restrict__ pts,
                                              double* __restrict__ partial) {
    int blk = blockIdx.x;
    int b = blk >> 6, c = blk & 63;
    const float4* base = (const float4*)(pts + ((size_t)b * NPTS + (size_t)c * MCHUNK) * 6);
    double s0 = 0, s1 = 0, s2 = 0;
    for (int i = threadIdx.x; i < MCHUNK / 2; i += 256) {
        float4 v0 = base[(size_t)i * 3];
        float4 v1 = base[(size_t)i * 3 + 1];
        float4 v2 = base[(size_t)i * 3 + 2];
        s0 += (double)v0.x + (double)v1.z;
        s1 += (double)v0.y + (double)v1.w;
        s2 += (double)v0.z + (double)v2.x;
    }
    for (int off = 32; off; off >>= 1) {
        s0 += __shfl_down(s0, off);
        s1 += __shfl_down(s1, off);
        s2 += __shfl_down(s2, off);
    }
    __shared__ double sh[4][3];
    int lane = threadIdx.x & 63, w = threadIdx.x >> 6;
    if (lane == 0) { sh[w][0] = s0; sh[w][1] = s1; sh[w][2] = s2; }
    __syncthreads();
    if (threadIdx.x == 0) {
        double t0 = 0, t1 = 0, t2 = 0;
        for (int q = 0; q < 4; q++) { t0 += sh[q][0]; t1 += sh[q][1]; t2 += sh[q][2]; }
        partial[(size_t)blk * 3 + 0] = t0;
        partial[(size_t)blk * 3 + 1] = t1;
        partial[(size_t)blk * 3 + 2] = t2;
    }
}

__global__ __launch_bounds__(64) void k_meanred(const double* __restrict__ partial,
                                                double* __restrict__ mean) {
    int b = threadIdx.x;
    if (b >= BATCH) return;
    double t0 = 0, t1 = 0, t2 = 0;
    for (int c = 0; c < NBLK_PER_B; c++) {
        const double* p = partial + ((size_t)b * NBLK_PER_B + c) * 3;
        t0 += p[0]; t1 += p[1]; t2 += p[2];
    }
    mean[b * 3 + 0] = t0 / (double)NPTS;
    mean[b * 3 + 1] = t1 / (double)NPTS;
    mean[b * 3 + 2] = t2 / (double)NPTS;
}

__global__ __launch_bounds__(256) void k_max(const float* __restrict__ pts,
                                             const double* __restrict__ mean,
                                             unsigned long long* __restrict__ maxsq) {
    int blk = blockIdx.x;
    int b = blk >> 6, c = blk & 63;
    double mx = mean[b * 3], my = mean[b * 3 + 1], mz = mean[b * 3 + 2];
    const float4* base = (const float4*)(pts + ((size_t)b * NPTS + (size_t)c * MCHUNK) * 6);
    double m = 0.0;
    for (int i = threadIdx.x; i < MCHUNK / 2; i += 256) {
        float4 v0 = base[(size_t)i * 3];
        float4 v1 = base[(size_t)i * 3 + 1];
        float4 v2 = base[(size_t)i * 3 + 2];
        double dx = (double)v0.x - mx, dy = (double)v0.y - my, dz = (double)v0.z - mz;
        m = fmax(m, dx * dx + dy * dy + dz * dz);
        dx = (double)v1.z - mx; dy = (double)v1.w - my; dz = (double)v2.x - mz;
        m = fmax(m, dx * dx + dy * dy + dz * dz);
    }
    for (int off = 32; off; off >>= 1)
        m = fmax(m, __shfl_down(m, off));
    __shared__ double sh[4];
    int lane = threadIdx.x & 63, w = threadIdx.x >> 6;
    if (lane == 0) sh[w] = m;
    __syncthreads();
    if (threadIdx.x == 0) {
        double t = fmax(fmax(sh[0], sh[1]), fmax(sh[2], sh[3]));
        atomicMax(&maxsq[b], (unsigned long long)__double_as_longlong(t));
    }
}

// One block per (batch, chunk, part). p = cell & 1 interleaved half-partition
// (balanced). 110 KB LDS half-grid -> only 2 streams of the input instead of 4.
// Unconditional fma transform (no divides), LDS accumulate, private store.
template <bool ATOMIC>
__global__ __launch_bounds__(1024, 4) void k_scatter_lds(const float* __restrict__ pts,
                                                         const double* __restrict__ mean,
                                                         const unsigned long long* __restrict__ maxsq,
                                                         float* __restrict__ accum) {
    __shared__ float acc[PCELLS][4];   // 110592 B (gfx950 LDS = 160 KiB/CU)
    int blk = blockIdx.x;
    int b = blk >> 3;
    int ch = (blk >> 1) & 3;
    int p = blk & 1;
    for (int c = threadIdx.x; c < PCELLS * 4; c += 1024)
        ((float*)acc)[c] = 0.0f;
    __syncthreads();

    double mx = mean[b * 3], my = mean[b * 3 + 1], mz = mean[b * 3 + 2];
    double inv = 1.0 / (2.0 * sqrt(__longlong_as_double((long long)maxsq[b])));

    const float4* base = (const float4*)(pts + ((size_t)b * NPTS + (size_t)ch * CPTS) * 6);

    auto point = [&](float x, float y, float z, float f1, float f2, float f3) {
        double vx = fma((double)x - mx, inv, 0.5) * 24.0;
        double vy = fma((double)y - my, inv, 0.5) * 24.0;
        double vz = fma((double)z - mz, inv, 0.5) * 24.0;
        vx = fmin(fmax(vx, 0.0), 23.0);
        vy = fmin(fmax(vy, 0.0), 23.0);
        vz = fmin(fmax(vz, 0.0), 23.0);
        int qx = (int)rint(vx);
        int qy = (int)rint(vy);
        int qz = (int)rint(vz);
        int cell = qx * (RES * RES) + qy * RES + qz;
        if ((cell & 1) == p) {
            int l = cell >> 1;
            atomicAdd(&acc[l][0], 1.0f);
            atomicAdd(&acc[l][1], f1);
            atomicAdd(&acc[l][2], f2);
            atomicAdd(&acc[l][3], f3);
        }
    };

    for (int it = 0; it < 8; ++it) {
        int pairA = it * 2048 + threadIdx.x;
        int pairB = pairA + 1024;
        float4 a0 = base[(size_t)pairA * 3];
        float4 a1 = base[(size_t)pairA * 3 + 1];
        float4 a2 = base[(size_t)pairA * 3 + 2];
        float4 b0 = base[(size_t)pairB * 3];
        float4 b1 = base[(size_t)pairB * 3 + 1];
        float4 b2 = base[(size_t)pairB * 3 + 2];
        point(a0.x, a0.y, a0.z, a0.w, a1.x, a1.y);
        point(a1.z, a1.w, a2.x, a2.y, a2.z, a2.w);
        point(b0.x, b0.y, b0.z, b0.w, b1.x, b1.y);
        point(b1.z, b1.w, b2.x, b2.y, b2.z, b2.w);
    }
    __syncthreads();

    if (ATOMIC) {
        // fallback: merge into shared per-batch accum; cell = (l<<1)|p
        for (int c = threadIdx.x; c < PCELLS * 4; c += 1024) {
            int l = c >> 2, f = c & 3;
            float v = acc[l][f];
            if (v != 0.0f)
                atomicAdd(&accum[((size_t)b * R3 + ((l << 1) | p)) * 4 + f], v);
        }
    } else {
        float4* gacc = (float4*)(accum + (size_t)blk * PCELLS * 4);
        const float4* lacc = (const float4*)acc;
        for (int c = threadIdx.x; c < PCELLS; c += 1024)
            gacc[c] = lacc[c];
    }
}

// Private-region finalize: cell r -> partition p = r&1, local l = r>>1.
__global__ __launch_bounds__(256) void k_final_priv(const float* __restrict__ accum,
                                                    float* __restrict__ out) {
    int cell = blockIdx.x * 256 + threadIdx.x;  // < BATCH*R3
    int b = cell / R3;
    int r = cell - b * R3;
    int p = r & 1;
    int l = r >> 1;
    const float4* a = (const float4*)accum;
    float4 s = make_float4(0.f, 0.f, 0.f, 0.f);
    #pragma unroll
    for (int ch = 0; ch < NCHUNK; ch++) {
        float4 v = a[((size_t)((b * NCHUNK + ch) * NPART + p)) * PCELLS + l];
        s.x += v.x; s.y += v.y; s.z += v.z; s.w += v.w;
    }
    size_t obase = (size_t)b * 4 * R3 + r;
    if (s.x > 0.0f) {
        out[obase]          = 1.0f;
        out[obase + R3]     = s.y / s.x;
        out[obase + 2 * R3] = s.z / s.x;
        out[obase + 3 * R3] = s.w / s.x;
    } else {
        out[obase]          = 0.0f;
        out[obase + R3]     = 0.0f;
        out[obase + 2 * R3] = 0.0f;
        out[obase + 3 * R3] = 0.0f;
    }
}

// Fallback finalize (shared accum)
__global__ __launch_bounds__(256) void k_final_sum(const float* __restrict__ accum,
                                                   float* __restrict__ out) {
    int cell = blockIdx.x * 256 + threadIdx.x;
    const float4 a = ((const float4*)accum)[cell];
    float cnt = a.x;
    int b = cell / R3;
    int r = cell - b * R3;
    size_t obase = (size_t)b * 4 * R3 + r;
    if (cnt > 0.0f) {
        out[obase]          = 1.0f;
        out[obase + R3]     = a.y / cnt;
        out[obase + 2 * R3] = a.z / cnt;
        out[obase + 3 * R3] = a.w / cnt;
    } else {
        out[obase]          = 0.0f;
        out[obase + R3]     = 0.0f;
        out[obase + 2 * R3] = 0.0f;
        out[obase + 3 * R3] = 0.0f;
    }
}

extern "C" void kernel_launch(void* const* d_in, const int* in_sizes, int n_in,
                              void* d_out, int out_size, void* d_ws, size_t ws_size,
                              hipStream_t stream) {
    const float* pts = (const float*)d_in[0];
    float* out = (float*)d_out;
    char* ws = (char*)d_ws;
    double* partial = (double*)(ws + WS_PARTIAL);
    double* mean = (double*)(ws + WS_MEAN);
    unsigned long long* maxsq = (unsigned long long*)(ws + WS_MAXSQ);
    float* accum = (float*)(ws + WS_ACCUM);
    bool priv = ws_size >= (size_t)WS_ACCUM + PRIV_BYTES;

    if (priv) {
        hipMemsetAsync(ws + WS_MAXSQ, 0, BATCH * sizeof(unsigned long long), stream);
    } else {
        hipMemsetAsync(ws + WS_MAXSQ, 0, (WS_ACCUM - WS_MAXSQ) + SHARED_BYTES, stream);
    }

    k_mean<<<BATCH * NBLK_PER_B, 256, 0, stream>>>(pts, partial);
    k_meanred<<<1, 64, 0, stream>>>(partial, mean);
    k_max<<<BATCH * NBLK_PER_B, 256, 0, stream>>>(pts, mean, maxsq);
    if (priv) {
        k_scatter_lds<false><<<NSCAT, 1024, 0, stream>>>(pts, mean, maxsq, accum);
        k_final_priv<<<(BATCH * R3) / 256, 256, 0, stream>>>(accum, out);
    } else {
        k_scatter_lds<true><<<NSCAT, 1024, 0, stream>>>(pts, mean, maxsq, accum);
        k_final_sum<<<(BATCH * R3) / 256, 256, 0, stream>>>(accum, out);
    }
}